// Round 5
// baseline (467.898 us; speedup 1.0000x reference)
//
#include <hip/hip_runtime.h>
#include <hip/hip_bf16.h>

// Problem: B=16, C=256, H=64, L=40, TD=768, NC=8, EMB=392
// R5: conv3x3 v3 = register-prefetched staging + fully unrolled kk loop.
//     final v2 = bf16 [co][x] restage + coalesced img/store epilogue.
//     fast __expf silu/tanh in hot epilogues (f01, conv3x3).

#define DEVFN static __device__ __forceinline__

DEVFN float sigmoidf_(float x) { return 1.f / (1.f + expf(-x)); }       // precise (mlp/sigw)
DEVFN float siluf_(float y) { return y / (1.f + __expf(-y)); }          // fast (hot paths)
DEVFN float tanh_fast_(float x) { return 1.f - 2.f / (__expf(2.f * x) + 1.f); }

typedef __attribute__((ext_vector_type(8))) short bf16x8;
typedef __attribute__((ext_vector_type(4))) float f32x4;

DEVFN unsigned short f2bf_(float f) {
    union { __hip_bfloat16 b; unsigned short u; } cv;
    cv.b = __float2bfloat16(f);
    return cv.u;
}
DEVFN float bf2f_(unsigned short u) {
    union { unsigned short u; __hip_bfloat16 b; } cv;
    cv.u = u;
    return __bfloat162float(cv.b);
}

// ---------------- prep: pack all conv weights into MFMA B-fragment order ----------------
__global__ void prep_kernel(const float* __restrict__ Wv, const float* __restrict__ Wf1,
                            const float* __restrict__ Wf3, const float* __restrict__ Wf2,
                            short* __restrict__ WvB, short* __restrict__ W1B,
                            short* __restrict__ W3B, short* __restrict__ WB2) {
    int idx = blockIdx.x * 256 + threadIdx.x;
    if (idx < 65536) {
        int j    = idx & 7;
        int lane = (idx >> 3) & 63;
        int coT  = (idx >> 9) & 15;
        int ci32 = (idx >> 13) & 7;
        int co = coT * 16 + (lane & 15);
        int ci = ci32 * 32 + ((lane >> 4) << 3) + j;
        int src = co * 256 + ci;
        WvB[idx] = (short)f2bf_(Wv[src]);
        W1B[idx] = (short)f2bf_(Wf1[src]);
        W3B[idx] = (short)f2bf_(Wf3[src]);
    }
    int o = idx - 65536;
    if (o >= 0 && o < 589824) {
        int j    = o & 7;
        int lane = (o >> 3) & 63;
        int coT  = (o >> 9) & 15;
        int ci32 = (o >> 13) & 7;
        int kk   = o >> 16;
        int co = coT * 16 + (lane & 15);
        int ci = ci32 * 32 + ((lane >> 4) << 3) + j;
        WB2[o] = (short)f2bf_(Wf2[(co * 256 + ci) * 9 + kk]);
    }
}

// ---------------- lang average ----------------
__global__ void lang_kernel(const float* __restrict__ flang, const int* __restrict__ mask,
                            float* __restrict__ fa) {
    __shared__ float inc[40];
    __shared__ float isum;
    int b = blockIdx.x, t = threadIdx.x;
    if (t == 0) {
        float cum[40];
        float c = 0.f;
        for (int l = 0; l < 40; ++l) { c += (float)mask[b * 40 + l]; cum[l] = c; }
        float tot = c, s = 0.f;
        for (int l = 0; l < 40; ++l) {
            float m = (float)mask[b * 40 + l];
            float v = (cum[l] > 1.f && cum[l] < tot) ? m : 0.f;
            inc[l] = v; s += v;
        }
        isum = s;
    }
    __syncthreads();
    for (int d = t; d < 768; d += 256) {
        float a = 0.f;
        for (int l = 0; l < 40; ++l) a += flang[(size_t)(b * 40 + l) * 768 + d] * inc[l];
        fa[b * 768 + d] = a / isum;
    }
}

// ---------------- lang MLP -> yc/xc ----------------
__global__ void mlp_kernel(const float* __restrict__ fa_g, const float* __restrict__ W1,
                           const float* __restrict__ b1, const float* __restrict__ W2,
                           const float* __restrict__ b2, float* __restrict__ ycxc) {
    __shared__ float fa[768];
    __shared__ float h[392];
    __shared__ float o[16];
    int b = blockIdx.x, t = threadIdx.x;
    for (int k = t; k < 768; k += 448) fa[k] = fa_g[b * 768 + k];
    __syncthreads();
    if (t < 392) {
        float a = b1[t];
        const float* w = W1 + (size_t)t * 768;
        for (int k = 0; k < 768; ++k) a = fmaf(fa[k], w[k], a);
        h[t] = a;
    }
    __syncthreads();
    if (t < 16) {
        float a = b2[t];
        const float* w = W2 + (size_t)t * 392;
        for (int k = 0; k < 392; ++k) a = fmaf(h[k], w[k], a);
        o[t] = sigmoidf_(a);
    }
    __syncthreads();
    if (t < 8) {
        ycxc[b * 8 + t]       = (float)(int)(o[2 * t] * 64.f);
        ycxc[128 + b * 8 + t] = (float)(int)(o[2 * t + 1] * 64.f);
    }
}

// ---------------- window sums for sigma (valid conv mean trick) ----------------
__global__ void wsum_kernel(const float* __restrict__ img, float* __restrict__ S) {
    __shared__ float red[9 * 256];
    int bc = blockIdx.x;            // b*256 + ci
    int t = threadIdx.x;
    float s[9];
#pragma unroll
    for (int k = 0; k < 9; ++k) s[k] = 0.f;
    const float* p = img + (size_t)bc * 4096;
    for (int j = 0; j < 16; ++j) {
        int idx = t + j * 256;
        int y = idx >> 6, x = idx & 63;
        float v = p[idx];
#pragma unroll
        for (int ky = 0; ky < 3; ++ky) {
            if (y < ky || y > ky + 61) continue;
#pragma unroll
            for (int kx = 0; kx < 3; ++kx) {
                if (x < kx || x > kx + 61) continue;
                s[ky * 3 + kx] += v;
            }
        }
    }
#pragma unroll
    for (int k = 0; k < 9; ++k) red[k * 256 + t] = s[k];
    __syncthreads();
    for (int st = 128; st > 0; st >>= 1) {
        if (t < st) {
#pragma unroll
            for (int k = 0; k < 9; ++k) red[k * 256 + t] += red[k * 256 + t + st];
        }
        __syncthreads();
    }
    if (t < 9) S[(size_t)bc * 9 + t] = red[t * 256];
}

__global__ void sigw_kernel(const float* __restrict__ Ws, const float* __restrict__ S,
                            const float* __restrict__ bs, float* __restrict__ sigw) {
    __shared__ float red[8 * 256];
    int b = blockIdx.x, t = threadIdx.x;    // t = ci
    float sv[9];
    const float* Sp = S + (size_t)(b * 256 + t) * 9;
#pragma unroll
    for (int k = 0; k < 9; ++k) sv[k] = Sp[k];
#pragma unroll
    for (int co = 0; co < 8; ++co) {
        const float* wp = Ws + (size_t)(co * 256 + t) * 9;
        float a = 0.f;
#pragma unroll
        for (int k = 0; k < 9; ++k) a = fmaf(wp[k], sv[k], a);
        red[co * 256 + t] = a;
    }
    __syncthreads();
    for (int st = 128; st > 0; st >>= 1) {
        if (t < st) {
#pragma unroll
            for (int co = 0; co < 8; ++co) red[co * 256 + t] += red[co * 256 + t + st];
        }
        __syncthreads();
    }
    if (t < 8) sigw[b * 8 + t] = sigmoidf_(red[t * 256] / 3844.f + bs[t]);
}

// ---------------- gaussian -> gamma/beta -> g, bmax ----------------
__global__ void gauss_kernel(const float* __restrict__ ycxc, const float* __restrict__ sigw,
                             const float* __restrict__ sigma_w,
                             const float* __restrict__ Wg, const float* __restrict__ sg,
                             const float* __restrict__ bg,
                             const float* __restrict__ Wb, const float* __restrict__ sb,
                             const float* __restrict__ bb,
                             float* __restrict__ g, float* __restrict__ bm) {
    int blk = blockIdx.x;
    int b = blk >> 6, y = blk & 63;
    int x = threadIdx.x;
    float sx = sigma_w[0] * 64.f;
    float w[8];
#pragma unroll
    for (int n = 0; n < 8; ++n) {
        float yc = ycxc[b * 8 + n], xc = ycxc[128 + b * 8 + n];
        float sy = sx * sigw[b * 8 + n];
        float dy = (float)y - yc, dx = (float)x - xc;
        w[n] = expf(-(dy * dy / (2.f * sy * sy) + dx * dx / (2.f * sx * sx)));
    }
    float gacc = 0.f, bmax = -3.4e38f;
#pragma unroll
    for (int n = 0; n < 8; ++n) {
        float a1 = 0.f, a2 = 0.f;
#pragma unroll
        for (int m = 0; m < 8; ++m) {
            a1 = fmaf(Wg[n * 8 + m], w[m], a1);
            a2 = fmaf(Wb[n * 8 + m], w[m], a2);
        }
        float ga = tanhf(siluf_(a1 * sg[n] + bg[n]));
        float be = tanhf(siluf_(a2 * sb[n] + bb[n]));
        gacc += ga;
        bmax = fmaxf(bmax, be);
    }
    g[(size_t)(b * 64 + y) * 64 + x] = gacc * 0.125f;
    bm[(size_t)(b * 64 + y) * 64 + x] = bmax;
}

// ---------------- fused: Wv 1x1 + tanh(silu) + FiLM + l2norm + Wf1 1x1 + silu ----------------
__global__ __launch_bounds__(256) void f01_kernel(
        const float* __restrict__ img, const short* __restrict__ wvb,
        const short* __restrict__ w1b,
        const float* __restrict__ sv, const float* __restrict__ bv,
        const float* __restrict__ s1, const float* __restrict__ b1,
        const float* __restrict__ g, const float* __restrict__ bm,
        __hip_bfloat16* __restrict__ outB) {
    __shared__ __attribute__((aligned(16))) short lA[64 * 264];   // 33792 B
    __shared__ float invs[64];
    __shared__ float ls_sv[256], ls_bv[256], ls_s1[256], ls_b1[256];
    __shared__ float ls_g[64], ls_bm[64];
    float* pr = (float*)lA;                                        // alias (sequenced)
    int blk = blockIdx.x, b = blk >> 6, y = blk & 63;
    int t = threadIdx.x, w = t >> 6, lane = t & 63;
    int lx = lane & 15, koct = lane >> 4;

    ls_sv[t] = sv[t]; ls_bv[t] = bv[t];
    ls_s1[t] = s1[t]; ls_b1[t] = b1[t];
    if (t < 64) {
        ls_g[t]  = g[(size_t)(b * 64 + y) * 64 + t];
        ls_bm[t] = bm[(size_t)(b * 64 + y) * 64 + t];
    }

    // stage img (fp32 NCHW) -> lA bf16 [x][ci]
    {
        int x = t & 63, cg = t >> 6;
        const float* ib = img + (size_t)b * 1048576 + y * 64 + x;
#pragma unroll
        for (int c8 = 0; c8 < 8; ++c8) {
            int ci0 = cg * 64 + c8 * 8;
            unsigned short r[8];
#pragma unroll
            for (int j = 0; j < 8; ++j) r[j] = f2bf_(ib[(size_t)(ci0 + j) * 4096]);
            *(uint4*)&lA[x * 264 + ci0] = *(uint4*)r;
        }
    }
    f32x4 acc[4][4];
#pragma unroll
    for (int mi = 0; mi < 4; ++mi)
#pragma unroll
        for (int ni = 0; ni < 4; ++ni) acc[mi][ni] = (f32x4){0.f, 0.f, 0.f, 0.f};
    __syncthreads();

    // GEMM1: Wv
#pragma unroll
    for (int k32 = 0; k32 < 8; ++k32) {
        const short* wp = wvb + (((k32 * 16) + w * 4) * 64 + lane) * 8;
        bf16x8 bfr[4];
#pragma unroll
        for (int ni = 0; ni < 4; ++ni) bfr[ni] = *(const bf16x8*)(wp + ni * 512);
        bf16x8 afr[4];
#pragma unroll
        for (int mi = 0; mi < 4; ++mi)
            afr[mi] = *(const bf16x8*)&lA[(mi * 16 + lx) * 264 + k32 * 32 + koct * 8];
#pragma unroll
        for (int mi = 0; mi < 4; ++mi)
#pragma unroll
            for (int ni = 0; ni < 4; ++ni)
                acc[mi][ni] = __builtin_amdgcn_mfma_f32_16x16x32_bf16(afr[mi], bfr[ni], acc[mi][ni], 0, 0, 0);
    }
    __syncthreads();   // lA (img) dead; pr may now be written

    // film epilogue: mv = tanh(silu(acc*sv+bv)); v = g*mv + bmax; partial l2
#pragma unroll
    for (int mi = 0; mi < 4; ++mi)
#pragma unroll
        for (int rr = 0; rr < 4; ++rr) {
            int x = mi * 16 + koct * 4 + rr;
            float ps = 0.f;
#pragma unroll
            for (int ni = 0; ni < 4; ++ni) {
                int co = w * 64 + ni * 16 + lx;
                float yv = fmaf(acc[mi][ni][rr], ls_sv[co], ls_bv[co]);
                float mvv = tanh_fast_(siluf_(yv));
                float v = fmaf(ls_g[x], mvv, ls_bm[x]);
                acc[mi][ni][rr] = v;
                ps += v * v;
            }
            pr[x * 64 + w * 16 + lx] = ps;
        }
    __syncthreads();
    if (t < 64) {
        float s2 = 0.f;
        for (int q = 0; q < 64; ++q) s2 += pr[t * 64 + q];
        invs[t] = 1.f / fmaxf(sqrtf(s2), 1e-12f);
    }
    __syncthreads();   // pr dead; lA may be rewritten (v)

    // v (normalized) -> lA bf16 [x][ci]
#pragma unroll
    for (int mi = 0; mi < 4; ++mi)
#pragma unroll
        for (int ni = 0; ni < 4; ++ni) {
            int co = w * 64 + ni * 16 + lx;
#pragma unroll
            for (int rr = 0; rr < 4; ++rr) {
                int x = mi * 16 + koct * 4 + rr;
                lA[x * 264 + co] = (short)f2bf_(acc[mi][ni][rr] * invs[x]);
            }
        }
#pragma unroll
    for (int mi = 0; mi < 4; ++mi)
#pragma unroll
        for (int ni = 0; ni < 4; ++ni) acc[mi][ni] = (f32x4){0.f, 0.f, 0.f, 0.f};
    __syncthreads();

    // GEMM2: Wf1
#pragma unroll
    for (int k32 = 0; k32 < 8; ++k32) {
        const short* wp = w1b + (((k32 * 16) + w * 4) * 64 + lane) * 8;
        bf16x8 bfr[4];
#pragma unroll
        for (int ni = 0; ni < 4; ++ni) bfr[ni] = *(const bf16x8*)(wp + ni * 512);
        bf16x8 afr[4];
#pragma unroll
        for (int mi = 0; mi < 4; ++mi)
            afr[mi] = *(const bf16x8*)&lA[(mi * 16 + lx) * 264 + k32 * 32 + koct * 8];
#pragma unroll
        for (int mi = 0; mi < 4; ++mi)
#pragma unroll
            for (int ni = 0; ni < 4; ++ni)
                acc[mi][ni] = __builtin_amdgcn_mfma_f32_16x16x32_bf16(afr[mi], bfr[ni], acc[mi][ni], 0, 0, 0);
    }
    __syncthreads();

    // silu -> lA [x][co] -> NHWC store
#pragma unroll
    for (int mi = 0; mi < 4; ++mi)
#pragma unroll
        for (int ni = 0; ni < 4; ++ni) {
            int co = w * 64 + ni * 16 + lx;
#pragma unroll
            for (int rr = 0; rr < 4; ++rr) {
                int x = mi * 16 + koct * 4 + rr;
                float yv = fmaf(acc[mi][ni][rr], ls_s1[co], ls_b1[co]);
                lA[x * 264 + co] = (short)f2bf_(siluf_(yv));
            }
        }
    __syncthreads();
    unsigned short* og = (unsigned short*)outB + (size_t)(b * 64 + y) * 16384;
#pragma unroll
    for (int it = 0; it < 8; ++it) {
        int e8 = t + it * 256;
        int x2 = e8 >> 5, c8 = e8 & 31;
        *(uint4*)(og + e8 * 8) = *(uint4*)&lA[x2 * 264 + c8 * 8];
    }
}

// ---------------- 3x3 conv v3: prefetched staging + unrolled kk ----------------
__global__ __launch_bounds__(256, 2) void conv3x3_mfma(const __hip_bfloat16* __restrict__ xin,
                                                       const short* __restrict__ wb,
                                                       const float* __restrict__ sc,
                                                       const float* __restrict__ bi,
                                                       __hip_bfloat16* __restrict__ outB) {
    __shared__ __attribute__((aligned(16))) short lds[4 * 66 * 72];   // 38016 B
    int blk = blockIdx.x;
    int b = blk >> 5, y0 = (blk & 31) * 2;
    int t = threadIdx.x;
    int w = t >> 6, lane = t & 63;
    int lx = lane & 15, koct = lane >> 4;
    const unsigned short* xg = (const unsigned short*)xin + (size_t)b * 1048576;

    // per-thread staging slots (9 x 16B): u = t + p*256 < 2112 = 4 rows * 66 xp * 8 ci8
    int goff[9], loff[9];
    bool uval[9], uin[9];
#pragma unroll
    for (int p = 0; p < 9; ++p) {
        int u = t + p * 256;
        uval[p] = (u < 2112);
        int r = u / 528;
        int rem = u - r * 528;
        int xp = rem >> 3, ci8 = rem & 7;
        int ys = y0 + r - 1, xs = xp - 1;
        uin[p] = uval[p] && ys >= 0 && ys < 64 && xs >= 0 && xs < 64;
        goff[p] = (ys * 64 + xs) * 256 + ci8 * 8;
        loff[p] = (r * 66 + xp) * 72 + ci8 * 8;
    }
    uint4 pf[9];

    f32x4 acc[8][4];
#pragma unroll
    for (int mi = 0; mi < 8; ++mi)
#pragma unroll
        for (int ni = 0; ni < 4; ++ni) acc[mi][ni] = (f32x4){0.f, 0.f, 0.f, 0.f};

    // prime cc=0
#pragma unroll
    for (int p = 0; p < 9; ++p) {
        uint4 v = {0u, 0u, 0u, 0u};
        if (uin[p]) v = *(const uint4*)(xg + goff[p]);
        pf[p] = v;
    }
#pragma unroll
    for (int p = 0; p < 9; ++p)
        if (uval[p]) *(uint4*)&lds[loff[p]] = pf[p];
    __syncthreads();

    for (int cc = 0; cc < 4; ++cc) {        // ci chunks of 64
        // prefetch next chunk into registers (overlaps with MFMA below)
        if (cc < 3) {
#pragma unroll
            for (int p = 0; p < 9; ++p) {
                uint4 v = {0u, 0u, 0u, 0u};
                if (uin[p]) v = *(const uint4*)(xg + goff[p] + (cc + 1) * 64);
                pf[p] = v;
            }
        }
#pragma unroll
        for (int kk = 0; kk < 9; ++kk) {
            int ky = kk / 3, kx = kk - ky * 3;
#pragma unroll
            for (int k32 = 0; k32 < 2; ++k32) {
                const short* wp = wb + ((((kk * 8 + cc * 2 + k32) * 16) + w * 4) * 64 + lane) * 8;
                bf16x8 bfr[4];
#pragma unroll
                for (int ni = 0; ni < 4; ++ni)
                    bfr[ni] = *(const bf16x8*)(wp + ni * 512);
                bf16x8 afr[8];
#pragma unroll
                for (int mi = 0; mi < 8; ++mi) {
                    int row = mi >> 2, xb = (mi & 3) * 16;
                    afr[mi] = *(const bf16x8*)&lds[((row + ky) * 66 + xb + lx + kx) * 72 + k32 * 32 + koct * 8];
                }
#pragma unroll
                for (int mi = 0; mi < 8; ++mi)
#pragma unroll
                    for (int ni = 0; ni < 4; ++ni)
                        acc[mi][ni] = __builtin_amdgcn_mfma_f32_16x16x32_bf16(afr[mi], bfr[ni], acc[mi][ni], 0, 0, 0);
            }
        }
        __syncthreads();
        if (cc < 3) {
#pragma unroll
            for (int p = 0; p < 9; ++p)
                if (uval[p]) *(uint4*)&lds[loff[p]] = pf[p];
            __syncthreads();
        }
    }
    // epilogue: silu(acc*sc+bi) -> bf16 NHWC via LDS restage, one row at a time
#pragma unroll
    for (int r2 = 0; r2 < 2; ++r2) {
#pragma unroll
        for (int mi4 = 0; mi4 < 4; ++mi4) {
            int mi = r2 * 4 + mi4;
#pragma unroll
            for (int ni = 0; ni < 4; ++ni) {
                int co = w * 64 + ni * 16 + lx;
                float s = sc[co], bb2 = bi[co];
#pragma unroll
                for (int rr = 0; rr < 4; ++rr) {
                    int x = mi4 * 16 + koct * 4 + rr;
                    float yv = fmaf(acc[mi][ni][rr], s, bb2);
                    lds[x * 264 + co] = (short)f2bf_(siluf_(yv));
                }
            }
        }
        __syncthreads();
        unsigned short* og = (unsigned short*)outB + (size_t)(b * 64 + y0 + r2) * 16384;
#pragma unroll
        for (int it = 0; it < 8; ++it) {
            int e8 = t + it * 256;
            int x2 = e8 >> 5, c8 = e8 & 31;
            *(uint4*)(og + e8 * 8) = *(uint4*)&lds[x2 * 264 + c8 * 8];
        }
        __syncthreads();
    }
}

// ---------------- final v2: Wf3 1x1 + bf3, v_add, l2norm, coalesced epilogue ----------------
__global__ __launch_bounds__(256, 4) void final_mfma(const __hip_bfloat16* __restrict__ inB,
                                                     const short* __restrict__ w3b,
                                                     const float* __restrict__ bf3,
                                                     const float* __restrict__ img,
                                                     const float* __restrict__ addw,
                                                     float* __restrict__ outF) {
    __shared__ __attribute__((aligned(16))) short lA[64 * 264];   // GEMM A [x][ci]; then w [co][x] (66 stride)
    __shared__ float pr2[256];
    __shared__ float invs[64];
    __shared__ float ls_b[256];
    int blk = blockIdx.x, b = blk >> 6, y = blk & 63;
    int t = threadIdx.x, w = t >> 6, lane = t & 63;
    int lx = lane & 15, koct = lane >> 4;
    ls_b[t] = bf3[t];

    const unsigned short* xg = (const unsigned short*)inB + (size_t)(b * 64 + y) * 16384;
#pragma unroll
    for (int it = 0; it < 8; ++it) {
        int e8 = t + it * 256;
        int x2 = e8 >> 5, c8 = e8 & 31;
        *(uint4*)&lA[x2 * 264 + c8 * 8] = *(const uint4*)(xg + e8 * 8);
    }
    f32x4 acc[4][4];
#pragma unroll
    for (int mi = 0; mi < 4; ++mi)
#pragma unroll
        for (int ni = 0; ni < 4; ++ni) acc[mi][ni] = (f32x4){0.f, 0.f, 0.f, 0.f};
    __syncthreads();

#pragma unroll
    for (int k32 = 0; k32 < 8; ++k32) {
        const short* wp = w3b + (((k32 * 16) + w * 4) * 64 + lane) * 8;
        bf16x8 bfr[4];
#pragma unroll
        for (int ni = 0; ni < 4; ++ni) bfr[ni] = *(const bf16x8*)(wp + ni * 512);
        bf16x8 afr[4];
#pragma unroll
        for (int mi = 0; mi < 4; ++mi)
            afr[mi] = *(const bf16x8*)&lA[(mi * 16 + lx) * 264 + k32 * 32 + koct * 8];
#pragma unroll
        for (int mi = 0; mi < 4; ++mi)
#pragma unroll
            for (int ni = 0; ni < 4; ++ni)
                acc[mi][ni] = __builtin_amdgcn_mfma_f32_16x16x32_bf16(afr[mi], bfr[ni], acc[mi][ni], 0, 0, 0);
    }
    __syncthreads();   // lA (A-tile) dead

    // restage w = acc + bf3 as bf16 [co][x], stride 66 (v_film << img, bf16 ok)
#pragma unroll
    for (int mi = 0; mi < 4; ++mi)
#pragma unroll
        for (int ni = 0; ni < 4; ++ni) {
            int co = w * 64 + ni * 16 + lx;
            float b3 = ls_b[co];
#pragma unroll
            for (int rr = 0; rr < 4; ++rr) {
                int x = mi * 16 + koct * 4 + rr;
                lA[co * 66 + x] = (short)f2bf_(acc[mi][ni][rr] + b3);
            }
        }
    __syncthreads();

    float aw = tanhf(addw[0]);
    float ca = 1.f + aw, cb = 1.f - aw;
    int x = t & 63, cg = t >> 6;
    const float* ip = img + (size_t)b * 1048576 + y * 64 + x;
    // pass 1: sum of squares (coalesced img reads)
    float ss = 0.f;
#pragma unroll 8
    for (int j = 0; j < 64; ++j) {
        int co = cg * 64 + j;
        float v = fmaf(cb, bf2f_((unsigned short)lA[co * 66 + x]), ca * ip[(size_t)co * 4096]);
        ss += v * v;
    }
    pr2[cg * 64 + x] = ss;
    __syncthreads();
    if (t < 64)
        invs[t] = 1.f / fmaxf(sqrtf(pr2[t] + pr2[64 + t] + pr2[128 + t] + pr2[192 + t]), 1e-12f);
    __syncthreads();
    // pass 2: recompute + scaled coalesced store
    float iv = invs[x];
    float* op = outF + (size_t)b * 1048576 + y * 64 + x;
#pragma unroll 8
    for (int j = 0; j < 64; ++j) {
        int co = cg * 64 + j;
        float v = fmaf(cb, bf2f_((unsigned short)lA[co * 66 + x]), ca * ip[(size_t)co * 4096]);
        op[(size_t)co * 4096] = v * iv;
    }
}

// ---------------- launch ----------------
extern "C" void kernel_launch(void* const* d_in, const int* in_sizes, int n_in,
                              void* d_out, int out_size, void* d_ws, size_t ws_size,
                              hipStream_t stream) {
    const float* img     = (const float*)d_in[0];
    const float* flang   = (const float*)d_in[1];
    const int*   wmask   = (const int*)d_in[2];
    const float* sigma_w = (const float*)d_in[3];
    const float* W1      = (const float*)d_in[4];
    const float* b1      = (const float*)d_in[5];
    const float* W2      = (const float*)d_in[6];
    const float* b2      = (const float*)d_in[7];
    const float* Wv      = (const float*)d_in[8];
    const float* sv      = (const float*)d_in[9];
    const float* bv      = (const float*)d_in[10];
    const float* Wg      = (const float*)d_in[11];
    const float* sg      = (const float*)d_in[12];
    const float* bg      = (const float*)d_in[13];
    const float* Wb      = (const float*)d_in[14];
    const float* sb      = (const float*)d_in[15];
    const float* bb      = (const float*)d_in[16];
    const float* Wf1     = (const float*)d_in[17];
    const float* sf1     = (const float*)d_in[18];
    const float* bf1     = (const float*)d_in[19];
    const float* Wf2     = (const float*)d_in[20];
    const float* sf2     = (const float*)d_in[21];
    const float* bf2     = (const float*)d_in[22];
    const float* Wf3     = (const float*)d_in[23];
    const float* bf3     = (const float*)d_in[24];
    const float* Ws      = (const float*)d_in[25];
    const float* bs      = (const float*)d_in[26];
    const float* addw    = (const float*)d_in[27];
    float* out = (float*)d_out;
    float* ws  = (float*)d_ws;

    // workspace layout (float offsets)
    short* WvB  = (short*)ws;                     // 32768 f
    short* W1B  = (short*)(ws + 32768);           // 32768 f
    short* W3B  = (short*)(ws + 65536);           // 32768 f
    short* WB2  = (short*)(ws + 98304);           // 294912 f
    float* fa   = ws + 393216;                    // 12288
    float* ycxc = ws + 405504;                    // 256
    float* S    = ws + 405760;                    // 36864
    float* sigw = ws + 442624;                    // 128
    float* gmap = ws + 442752;                    // 65536
    float* bmap = ws + 508288;                    // 65536
    __hip_bfloat16* bufA = (__hip_bfloat16*)(ws + 573824);   // 16.78M bf16 NHWC
    __hip_bfloat16* bufB = (__hip_bfloat16*)(ws + 8962432);  // 16.78M bf16 NHWC

    prep_kernel<<<2560, 256, 0, stream>>>(Wv, Wf1, Wf3, Wf2, WvB, W1B, W3B, WB2);
    lang_kernel<<<16, 256, 0, stream>>>(flang, wmask, fa);
    mlp_kernel<<<16, 448, 0, stream>>>(fa, W1, b1, W2, b2, ycxc);
    wsum_kernel<<<4096, 256, 0, stream>>>(img, S);
    sigw_kernel<<<16, 256, 0, stream>>>(Ws, S, bs, sigw);
    gauss_kernel<<<1024, 64, 0, stream>>>(ycxc, sigw, sigma_w, Wg, sg, bg, Wb, sb, bb, gmap, bmap);
    // f1 = silu(Wf1 * l2norm(g*tanh(silu(Wv*img*sv+bv)) + bmax) * sf1 + bf1) -> bufB (bf16 NHWC)
    f01_kernel<<<1024, 256, 0, stream>>>(img, WvB, W1B, sv, bv, sf1, bf1, gmap, bmap, bufB);
    // f2 = silu(Wf2(3x3)*f1*sf2+bf2) -> bufA (bf16 NHWC)
    conv3x3_mfma<<<512, 256, 0, stream>>>(bufB, WB2, sf2, bf2, bufA);
    // out = l2norm((1+aw)*img + (1-aw)*(Wf3*f2 + bf3)) -> d_out (fp32 NCHW)
    final_mfma<<<1024, 256, 0, stream>>>(bufA, W3B, bf3, img, addw, out);
}

// Round 6
// 419.515 us; speedup vs baseline: 1.1153x; 1.1153x over previous
//
#include <hip/hip_runtime.h>
#include <hip/hip_bf16.h>

// Problem: B=16, C=256, H=64, L=40, TD=768, NC=8, EMB=392
// R6: conv3x3 v4 = async global_load_lds double-buffered staging (no VGPR
//     round-trip, no spills; R5's register prefetch spilled to scratch).
//     Border/pad lanes load from a 16B zero scratch so every issue's lane 0
//     is active (wave-uniform LDS base stays correct). lang+mlp merged.

#define DEVFN static __device__ __forceinline__

DEVFN float sigmoidf_(float x) { return 1.f / (1.f + expf(-x)); }       // precise (mlp/sigw)
DEVFN float siluf_(float y) { return y / (1.f + __expf(-y)); }          // fast (hot paths)
DEVFN float tanh_fast_(float x) { return 1.f - 2.f / (__expf(2.f * x) + 1.f); }

typedef __attribute__((ext_vector_type(8))) short bf16x8;
typedef __attribute__((ext_vector_type(4))) float f32x4;

DEVFN unsigned short f2bf_(float f) {
    union { __hip_bfloat16 b; unsigned short u; } cv;
    cv.b = __float2bfloat16(f);
    return cv.u;
}
DEVFN float bf2f_(unsigned short u) {
    union { unsigned short u; __hip_bfloat16 b; } cv;
    cv.u = u;
    return __bfloat162float(cv.b);
}

DEVFN void async_cp16(const void* g, void* l) {
    __builtin_amdgcn_global_load_lds(
        (const __attribute__((address_space(1))) unsigned int*)g,
        (__attribute__((address_space(3))) unsigned int*)l, 16, 0, 0);
}

// ---------------- prep: pack conv weights into MFMA B-fragment order + zero scratch ----------------
__global__ void prep_kernel(const float* __restrict__ Wv, const float* __restrict__ Wf1,
                            const float* __restrict__ Wf3, const float* __restrict__ Wf2,
                            short* __restrict__ WvB, short* __restrict__ W1B,
                            short* __restrict__ W3B, short* __restrict__ WB2,
                            float* __restrict__ zbuf) {
    int idx = blockIdx.x * 256 + threadIdx.x;
    if (idx < 8) zbuf[idx] = 0.f;
    if (idx < 65536) {
        int j    = idx & 7;
        int lane = (idx >> 3) & 63;
        int coT  = (idx >> 9) & 15;
        int ci32 = (idx >> 13) & 7;
        int co = coT * 16 + (lane & 15);
        int ci = ci32 * 32 + ((lane >> 4) << 3) + j;
        int src = co * 256 + ci;
        WvB[idx] = (short)f2bf_(Wv[src]);
        W1B[idx] = (short)f2bf_(Wf1[src]);
        W3B[idx] = (short)f2bf_(Wf3[src]);
    }
    int o = idx - 65536;
    if (o >= 0 && o < 589824) {
        int j    = o & 7;
        int lane = (o >> 3) & 63;
        int coT  = (o >> 9) & 15;
        int ci32 = (o >> 13) & 7;
        int kk   = o >> 16;
        int co = coT * 16 + (lane & 15);
        int ci = ci32 * 32 + ((lane >> 4) << 3) + j;
        WB2[o] = (short)f2bf_(Wf2[(co * 256 + ci) * 9 + kk]);
    }
}

// ---------------- lang average + MLP -> yc/xc (merged) ----------------
__global__ void langmlp_kernel(const float* __restrict__ flang, const int* __restrict__ mask,
                               const float* __restrict__ W1, const float* __restrict__ b1,
                               const float* __restrict__ W2, const float* __restrict__ b2,
                               float* __restrict__ ycxc) {
    __shared__ float inc[40];
    __shared__ float isum;
    __shared__ float fa[768];
    __shared__ float h[392];
    __shared__ float o[16];
    int b = blockIdx.x, t = threadIdx.x;
    if (t == 0) {
        float cum[40];
        float c = 0.f;
        for (int l = 0; l < 40; ++l) { c += (float)mask[b * 40 + l]; cum[l] = c; }
        float tot = c, s = 0.f;
        for (int l = 0; l < 40; ++l) {
            float m = (float)mask[b * 40 + l];
            float v = (cum[l] > 1.f && cum[l] < tot) ? m : 0.f;
            inc[l] = v; s += v;
        }
        isum = s;
    }
    __syncthreads();
    for (int d = t; d < 768; d += 448) {
        float a = 0.f;
        for (int l = 0; l < 40; ++l) a += flang[(size_t)(b * 40 + l) * 768 + d] * inc[l];
        fa[d] = a / isum;
    }
    __syncthreads();
    if (t < 392) {
        float a = b1[t];
        const float* w = W1 + (size_t)t * 768;
        for (int k = 0; k < 768; ++k) a = fmaf(fa[k], w[k], a);
        h[t] = a;
    }
    __syncthreads();
    if (t < 16) {
        float a = b2[t];
        const float* w = W2 + (size_t)t * 392;
        for (int k = 0; k < 392; ++k) a = fmaf(h[k], w[k], a);
        o[t] = sigmoidf_(a);
    }
    __syncthreads();
    if (t < 8) {
        ycxc[b * 8 + t]       = (float)(int)(o[2 * t] * 64.f);
        ycxc[128 + b * 8 + t] = (float)(int)(o[2 * t + 1] * 64.f);
    }
}

// ---------------- window sums for sigma (valid conv mean trick) ----------------
__global__ void wsum_kernel(const float* __restrict__ img, float* __restrict__ S) {
    __shared__ float red[9 * 256];
    int bc = blockIdx.x;            // b*256 + ci
    int t = threadIdx.x;
    float s[9];
#pragma unroll
    for (int k = 0; k < 9; ++k) s[k] = 0.f;
    const float* p = img + (size_t)bc * 4096;
    for (int j = 0; j < 16; ++j) {
        int idx = t + j * 256;
        int y = idx >> 6, x = idx & 63;
        float v = p[idx];
#pragma unroll
        for (int ky = 0; ky < 3; ++ky) {
            if (y < ky || y > ky + 61) continue;
#pragma unroll
            for (int kx = 0; kx < 3; ++kx) {
                if (x < kx || x > kx + 61) continue;
                s[ky * 3 + kx] += v;
            }
        }
    }
#pragma unroll
    for (int k = 0; k < 9; ++k) red[k * 256 + t] = s[k];
    __syncthreads();
    for (int st = 128; st > 0; st >>= 1) {
        if (t < st) {
#pragma unroll
            for (int k = 0; k < 9; ++k) red[k * 256 + t] += red[k * 256 + t + st];
        }
        __syncthreads();
    }
    if (t < 9) S[(size_t)bc * 9 + t] = red[t * 256];
}

__global__ void sigw_kernel(const float* __restrict__ Ws, const float* __restrict__ S,
                            const float* __restrict__ bs, float* __restrict__ sigw) {
    __shared__ float red[8 * 256];
    int b = blockIdx.x, t = threadIdx.x;    // t = ci
    float sv[9];
    const float* Sp = S + (size_t)(b * 256 + t) * 9;
#pragma unroll
    for (int k = 0; k < 9; ++k) sv[k] = Sp[k];
#pragma unroll
    for (int co = 0; co < 8; ++co) {
        const float* wp = Ws + (size_t)(co * 256 + t) * 9;
        float a = 0.f;
#pragma unroll
        for (int k = 0; k < 9; ++k) a = fmaf(wp[k], sv[k], a);
        red[co * 256 + t] = a;
    }
    __syncthreads();
    for (int st = 128; st > 0; st >>= 1) {
        if (t < st) {
#pragma unroll
            for (int co = 0; co < 8; ++co) red[co * 256 + t] += red[co * 256 + t + st];
        }
        __syncthreads();
    }
    if (t < 8) sigw[b * 8 + t] = sigmoidf_(red[t * 256] / 3844.f + bs[t]);
}

// ---------------- gaussian -> gamma/beta -> g, bmax ----------------
__global__ void gauss_kernel(const float* __restrict__ ycxc, const float* __restrict__ sigw,
                             const float* __restrict__ sigma_w,
                             const float* __restrict__ Wg, const float* __restrict__ sg,
                             const float* __restrict__ bg,
                             const float* __restrict__ Wb, const float* __restrict__ sb,
                             const float* __restrict__ bb,
                             float* __restrict__ g, float* __restrict__ bm) {
    int blk = blockIdx.x;
    int b = blk >> 6, y = blk & 63;
    int x = threadIdx.x;
    float sx = sigma_w[0] * 64.f;
    float w[8];
#pragma unroll
    for (int n = 0; n < 8; ++n) {
        float yc = ycxc[b * 8 + n], xc = ycxc[128 + b * 8 + n];
        float sy = sx * sigw[b * 8 + n];
        float dy = (float)y - yc, dx = (float)x - xc;
        w[n] = expf(-(dy * dy / (2.f * sy * sy) + dx * dx / (2.f * sx * sx)));
    }
    float gacc = 0.f, bmax = -3.4e38f;
#pragma unroll
    for (int n = 0; n < 8; ++n) {
        float a1 = 0.f, a2 = 0.f;
#pragma unroll
        for (int m = 0; m < 8; ++m) {
            a1 = fmaf(Wg[n * 8 + m], w[m], a1);
            a2 = fmaf(Wb[n * 8 + m], w[m], a2);
        }
        float ga = tanhf(siluf_(a1 * sg[n] + bg[n]));
        float be = tanhf(siluf_(a2 * sb[n] + bb[n]));
        gacc += ga;
        bmax = fmaxf(bmax, be);
    }
    g[(size_t)(b * 64 + y) * 64 + x] = gacc * 0.125f;
    bm[(size_t)(b * 64 + y) * 64 + x] = bmax;
}

// ---------------- fused: Wv 1x1 + tanh(silu) + FiLM + l2norm + Wf1 1x1 + silu ----------------
__global__ __launch_bounds__(256) void f01_kernel(
        const float* __restrict__ img, const short* __restrict__ wvb,
        const short* __restrict__ w1b,
        const float* __restrict__ sv, const float* __restrict__ bv,
        const float* __restrict__ s1, const float* __restrict__ b1,
        const float* __restrict__ g, const float* __restrict__ bm,
        __hip_bfloat16* __restrict__ outB) {
    __shared__ __attribute__((aligned(16))) short lA[64 * 264];   // 33792 B
    __shared__ float invs[64];
    __shared__ float ls_sv[256], ls_bv[256], ls_s1[256], ls_b1[256];
    __shared__ float ls_g[64], ls_bm[64];
    float* pr = (float*)lA;                                        // alias (sequenced)
    int blk = blockIdx.x, b = blk >> 6, y = blk & 63;
    int t = threadIdx.x, w = t >> 6, lane = t & 63;
    int lx = lane & 15, koct = lane >> 4;

    ls_sv[t] = sv[t]; ls_bv[t] = bv[t];
    ls_s1[t] = s1[t]; ls_b1[t] = b1[t];
    if (t < 64) {
        ls_g[t]  = g[(size_t)(b * 64 + y) * 64 + t];
        ls_bm[t] = bm[(size_t)(b * 64 + y) * 64 + t];
    }

    // stage img (fp32 NCHW) -> lA bf16 [x][ci]
    {
        int x = t & 63, cg = t >> 6;
        const float* ib = img + (size_t)b * 1048576 + y * 64 + x;
#pragma unroll
        for (int c8 = 0; c8 < 8; ++c8) {
            int ci0 = cg * 64 + c8 * 8;
            unsigned short r[8];
#pragma unroll
            for (int j = 0; j < 8; ++j) r[j] = f2bf_(ib[(size_t)(ci0 + j) * 4096]);
            *(uint4*)&lA[x * 264 + ci0] = *(uint4*)r;
        }
    }
    f32x4 acc[4][4];
#pragma unroll
    for (int mi = 0; mi < 4; ++mi)
#pragma unroll
        for (int ni = 0; ni < 4; ++ni) acc[mi][ni] = (f32x4){0.f, 0.f, 0.f, 0.f};
    __syncthreads();

    // GEMM1: Wv
#pragma unroll
    for (int k32 = 0; k32 < 8; ++k32) {
        const short* wp = wvb + (((k32 * 16) + w * 4) * 64 + lane) * 8;
        bf16x8 bfr[4];
#pragma unroll
        for (int ni = 0; ni < 4; ++ni) bfr[ni] = *(const bf16x8*)(wp + ni * 512);
        bf16x8 afr[4];
#pragma unroll
        for (int mi = 0; mi < 4; ++mi)
            afr[mi] = *(const bf16x8*)&lA[(mi * 16 + lx) * 264 + k32 * 32 + koct * 8];
#pragma unroll
        for (int mi = 0; mi < 4; ++mi)
#pragma unroll
            for (int ni = 0; ni < 4; ++ni)
                acc[mi][ni] = __builtin_amdgcn_mfma_f32_16x16x32_bf16(afr[mi], bfr[ni], acc[mi][ni], 0, 0, 0);
    }
    __syncthreads();   // lA (img) dead; pr may now be written

    // film epilogue: mv = tanh(silu(acc*sv+bv)); v = g*mv + bmax; partial l2
#pragma unroll
    for (int mi = 0; mi < 4; ++mi)
#pragma unroll
        for (int rr = 0; rr < 4; ++rr) {
            int x = mi * 16 + koct * 4 + rr;
            float ps = 0.f;
#pragma unroll
            for (int ni = 0; ni < 4; ++ni) {
                int co = w * 64 + ni * 16 + lx;
                float yv = fmaf(acc[mi][ni][rr], ls_sv[co], ls_bv[co]);
                float mvv = tanh_fast_(siluf_(yv));
                float v = fmaf(ls_g[x], mvv, ls_bm[x]);
                acc[mi][ni][rr] = v;
                ps += v * v;
            }
            pr[x * 64 + w * 16 + lx] = ps;
        }
    __syncthreads();
    if (t < 64) {
        float s2 = 0.f;
        for (int q = 0; q < 64; ++q) s2 += pr[t * 64 + q];
        invs[t] = 1.f / fmaxf(sqrtf(s2), 1e-12f);
    }
    __syncthreads();   // pr dead; lA may be rewritten (v)

    // v (normalized) -> lA bf16 [x][ci]
#pragma unroll
    for (int mi = 0; mi < 4; ++mi)
#pragma unroll
        for (int ni = 0; ni < 4; ++ni) {
            int co = w * 64 + ni * 16 + lx;
#pragma unroll
            for (int rr = 0; rr < 4; ++rr) {
                int x = mi * 16 + koct * 4 + rr;
                lA[x * 264 + co] = (short)f2bf_(acc[mi][ni][rr] * invs[x]);
            }
        }
#pragma unroll
    for (int mi = 0; mi < 4; ++mi)
#pragma unroll
        for (int ni = 0; ni < 4; ++ni) acc[mi][ni] = (f32x4){0.f, 0.f, 0.f, 0.f};
    __syncthreads();

    // GEMM2: Wf1
#pragma unroll
    for (int k32 = 0; k32 < 8; ++k32) {
        const short* wp = w1b + (((k32 * 16) + w * 4) * 64 + lane) * 8;
        bf16x8 bfr[4];
#pragma unroll
        for (int ni = 0; ni < 4; ++ni) bfr[ni] = *(const bf16x8*)(wp + ni * 512);
        bf16x8 afr[4];
#pragma unroll
        for (int mi = 0; mi < 4; ++mi)
            afr[mi] = *(const bf16x8*)&lA[(mi * 16 + lx) * 264 + k32 * 32 + koct * 8];
#pragma unroll
        for (int mi = 0; mi < 4; ++mi)
#pragma unroll
            for (int ni = 0; ni < 4; ++ni)
                acc[mi][ni] = __builtin_amdgcn_mfma_f32_16x16x32_bf16(afr[mi], bfr[ni], acc[mi][ni], 0, 0, 0);
    }
    __syncthreads();

    // silu -> lA [x][co] -> NHWC store
#pragma unroll
    for (int mi = 0; mi < 4; ++mi)
#pragma unroll
        for (int ni = 0; ni < 4; ++ni) {
            int co = w * 64 + ni * 16 + lx;
#pragma unroll
            for (int rr = 0; rr < 4; ++rr) {
                int x = mi * 16 + koct * 4 + rr;
                float yv = fmaf(acc[mi][ni][rr], ls_s1[co], ls_b1[co]);
                lA[x * 264 + co] = (short)f2bf_(siluf_(yv));
            }
        }
    __syncthreads();
    unsigned short* og = (unsigned short*)outB + (size_t)(b * 64 + y) * 16384;
#pragma unroll
    for (int it = 0; it < 8; ++it) {
        int e8 = t + it * 256;
        int x2 = e8 >> 5, c8 = e8 & 31;
        *(uint4*)(og + e8 * 8) = *(uint4*)&lA[x2 * 264 + c8 * 8];
    }
}

// ---------------- 3x3 conv v4: async global_load_lds double-buffered ----------------
// LDS tile per chunk: [r(4)][xp(66)][72 shorts] = 38016 B. Slot = unit*9+oct,
// oct<8 = data octet (16B), oct==8 = pad (loads zeros). Border/halo lanes load
// from zbuf (16B zeros) so every issue keeps lane 0 active (uniform LDS base).
DEVFN void stage_chunk(const unsigned short* __restrict__ xg, short* ldsbuf,
                       const unsigned short* __restrict__ zbuf, int cc, int y0, int t) {
#pragma unroll
    for (int p = 0; p < 10; ++p) {
        int slot = t + p * 256;
        if (slot < 2376) {                       // 4 rows * 66 xp * 9
            int r = slot / 594;
            int rem = slot - r * 594;
            int xp = rem / 9;
            int oct = rem - xp * 9;
            int ys = y0 + r - 1, xs = xp - 1;
            bool valid = (oct < 8) && (ys >= 0) && (ys < 64) && (xs >= 0) && (xs < 64);
            const unsigned short* gp = valid ? (xg + ((ys * 64 + xs) * 256 + cc * 64 + oct * 8))
                                             : zbuf;
            async_cp16(gp, ldsbuf + slot * 8);
        }
    }
}

__global__ __launch_bounds__(256, 2) void conv3x3_mfma(const __hip_bfloat16* __restrict__ xin,
                                                       const short* __restrict__ wb,
                                                       const float* __restrict__ sc,
                                                       const float* __restrict__ bi,
                                                       const float* __restrict__ zbufF,
                                                       __hip_bfloat16* __restrict__ outB) {
    __shared__ __attribute__((aligned(16))) short lds[2][19008];   // 2 x 38016 B
    int blk = blockIdx.x;
    int b = blk >> 5, y0 = (blk & 31) * 2;
    int t = threadIdx.x;
    int w = t >> 6, lane = t & 63;
    int lx = lane & 15, koct = lane >> 4;
    const unsigned short* xg = (const unsigned short*)xin + (size_t)b * 1048576;
    const unsigned short* zbuf = (const unsigned short*)zbufF;

    f32x4 acc[8][4];
#pragma unroll
    for (int mi = 0; mi < 8; ++mi)
#pragma unroll
        for (int ni = 0; ni < 4; ++ni) acc[mi][ni] = (f32x4){0.f, 0.f, 0.f, 0.f};

    stage_chunk(xg, lds[0], zbuf, 0, y0, t);
    __syncthreads();

    for (int cc = 0; cc < 4; ++cc) {        // ci chunks of 64
        short* cur = lds[cc & 1];
        if (cc < 3) stage_chunk(xg, lds[(cc + 1) & 1], zbuf, cc + 1, y0, t);
        for (int kk = 0; kk < 9; ++kk) {
            int ky = kk / 3, kx = kk - ky * 3;
#pragma unroll
            for (int k32 = 0; k32 < 2; ++k32) {
                const short* wp = wb + ((((kk * 8 + cc * 2 + k32) * 16) + w * 4) * 64 + lane) * 8;
                bf16x8 bfr[4];
#pragma unroll
                for (int ni = 0; ni < 4; ++ni)
                    bfr[ni] = *(const bf16x8*)(wp + ni * 512);
                bf16x8 afr[8];
#pragma unroll
                for (int mi = 0; mi < 8; ++mi) {
                    int row = mi >> 2, xb = (mi & 3) * 16;
                    afr[mi] = *(const bf16x8*)&cur[((row + ky) * 66 + xb + lx + kx) * 72 + k32 * 32 + koct * 8];
                }
#pragma unroll
                for (int mi = 0; mi < 8; ++mi)
#pragma unroll
                    for (int ni = 0; ni < 4; ++ni)
                        acc[mi][ni] = __builtin_amdgcn_mfma_f32_16x16x32_bf16(afr[mi], bfr[ni], acc[mi][ni], 0, 0, 0);
            }
        }
        __syncthreads();
    }
    // epilogue: silu(acc*sc+bi) -> bf16 NHWC via LDS restage (reuse lds[0]), per row
    short* ep = &lds[0][0];
#pragma unroll
    for (int r2 = 0; r2 < 2; ++r2) {
#pragma unroll
        for (int mi4 = 0; mi4 < 4; ++mi4) {
            int mi = r2 * 4 + mi4;
#pragma unroll
            for (int ni = 0; ni < 4; ++ni) {
                int co = w * 64 + ni * 16 + lx;
                float s = sc[co], bb2 = bi[co];
#pragma unroll
                for (int rr = 0; rr < 4; ++rr) {
                    int x = mi4 * 16 + koct * 4 + rr;
                    float yv = fmaf(acc[mi][ni][rr], s, bb2);
                    ep[x * 264 + co] = (short)f2bf_(siluf_(yv));
                }
            }
        }
        __syncthreads();
        unsigned short* og = (unsigned short*)outB + (size_t)(b * 64 + y0 + r2) * 16384;
#pragma unroll
        for (int it = 0; it < 8; ++it) {
            int e8 = t + it * 256;
            int x2 = e8 >> 5, c8 = e8 & 31;
            *(uint4*)(og + e8 * 8) = *(uint4*)&ep[x2 * 264 + c8 * 8];
        }
        __syncthreads();
    }
}

// ---------------- final v2: Wf3 1x1 + bf3, v_add, l2norm, coalesced epilogue ----------------
__global__ __launch_bounds__(256, 4) void final_mfma(const __hip_bfloat16* __restrict__ inB,
                                                     const short* __restrict__ w3b,
                                                     const float* __restrict__ bf3,
                                                     const float* __restrict__ img,
                                                     const float* __restrict__ addw,
                                                     float* __restrict__ outF) {
    __shared__ __attribute__((aligned(16))) short lA[64 * 264];   // GEMM A [x][ci]; then w [co][x] (66 stride)
    __shared__ float pr2[256];
    __shared__ float invs[64];
    __shared__ float ls_b[256];
    int blk = blockIdx.x, b = blk >> 6, y = blk & 63;
    int t = threadIdx.x, w = t >> 6, lane = t & 63;
    int lx = lane & 15, koct = lane >> 4;
    ls_b[t] = bf3[t];

    const unsigned short* xg = (const unsigned short*)inB + (size_t)(b * 64 + y) * 16384;
#pragma unroll
    for (int it = 0; it < 8; ++it) {
        int e8 = t + it * 256;
        int x2 = e8 >> 5, c8 = e8 & 31;
        *(uint4*)&lA[x2 * 264 + c8 * 8] = *(const uint4*)(xg + e8 * 8);
    }
    f32x4 acc[4][4];
#pragma unroll
    for (int mi = 0; mi < 4; ++mi)
#pragma unroll
        for (int ni = 0; ni < 4; ++ni) acc[mi][ni] = (f32x4){0.f, 0.f, 0.f, 0.f};
    __syncthreads();

#pragma unroll
    for (int k32 = 0; k32 < 8; ++k32) {
        const short* wp = w3b + (((k32 * 16) + w * 4) * 64 + lane) * 8;
        bf16x8 bfr[4];
#pragma unroll
        for (int ni = 0; ni < 4; ++ni) bfr[ni] = *(const bf16x8*)(wp + ni * 512);
        bf16x8 afr[4];
#pragma unroll
        for (int mi = 0; mi < 4; ++mi)
            afr[mi] = *(const bf16x8*)&lA[(mi * 16 + lx) * 264 + k32 * 32 + koct * 8];
#pragma unroll
        for (int mi = 0; mi < 4; ++mi)
#pragma unroll
            for (int ni = 0; ni < 4; ++ni)
                acc[mi][ni] = __builtin_amdgcn_mfma_f32_16x16x32_bf16(afr[mi], bfr[ni], acc[mi][ni], 0, 0, 0);
    }
    __syncthreads();   // lA (A-tile) dead

    // restage w = acc + bf3 as bf16 [co][x], stride 66 (v_film << img, bf16 ok)
#pragma unroll
    for (int mi = 0; mi < 4; ++mi)
#pragma unroll
        for (int ni = 0; ni < 4; ++ni) {
            int co = w * 64 + ni * 16 + lx;
            float b3 = ls_b[co];
#pragma unroll
            for (int rr = 0; rr < 4; ++rr) {
                int x = mi * 16 + koct * 4 + rr;
                lA[co * 66 + x] = (short)f2bf_(acc[mi][ni][rr] + b3);
            }
        }
    __syncthreads();

    float aw = tanhf(addw[0]);
    float ca = 1.f + aw, cb = 1.f - aw;
    int x = t & 63, cg = t >> 6;
    const float* ip = img + (size_t)b * 1048576 + y * 64 + x;
    // pass 1: sum of squares (coalesced img reads)
    float ss = 0.f;
#pragma unroll 8
    for (int j = 0; j < 64; ++j) {
        int co = cg * 64 + j;
        float v = fmaf(cb, bf2f_((unsigned short)lA[co * 66 + x]), ca * ip[(size_t)co * 4096]);
        ss += v * v;
    }
    pr2[cg * 64 + x] = ss;
    __syncthreads();
    if (t < 64)
        invs[t] = 1.f / fmaxf(sqrtf(pr2[t] + pr2[64 + t] + pr2[128 + t] + pr2[192 + t]), 1e-12f);
    __syncthreads();
    // pass 2: recompute + scaled coalesced store
    float iv = invs[x];
    float* op = outF + (size_t)b * 1048576 + y * 64 + x;
#pragma unroll 8
    for (int j = 0; j < 64; ++j) {
        int co = cg * 64 + j;
        float v = fmaf(cb, bf2f_((unsigned short)lA[co * 66 + x]), ca * ip[(size_t)co * 4096]);
        op[(size_t)co * 4096] = v * iv;
    }
}

// ---------------- launch ----------------
extern "C" void kernel_launch(void* const* d_in, const int* in_sizes, int n_in,
                              void* d_out, int out_size, void* d_ws, size_t ws_size,
                              hipStream_t stream) {
    const float* img     = (const float*)d_in[0];
    const float* flang   = (const float*)d_in[1];
    const int*   wmask   = (const int*)d_in[2];
    const float* sigma_w = (const float*)d_in[3];
    const float* W1      = (const float*)d_in[4];
    const float* b1      = (const float*)d_in[5];
    const float* W2      = (const float*)d_in[6];
    const float* b2      = (const float*)d_in[7];
    const float* Wv      = (const float*)d_in[8];
    const float* sv      = (const float*)d_in[9];
    const float* bv      = (const float*)d_in[10];
    const float* Wg      = (const float*)d_in[11];
    const float* sg      = (const float*)d_in[12];
    const float* bg      = (const float*)d_in[13];
    const float* Wb      = (const float*)d_in[14];
    const float* sb      = (const float*)d_in[15];
    const float* bb      = (const float*)d_in[16];
    const float* Wf1     = (const float*)d_in[17];
    const float* sf1     = (const float*)d_in[18];
    const float* bf1     = (const float*)d_in[19];
    const float* Wf2     = (const float*)d_in[20];
    const float* sf2     = (const float*)d_in[21];
    const float* bf2     = (const float*)d_in[22];
    const float* Wf3     = (const float*)d_in[23];
    const float* bf3     = (const float*)d_in[24];
    const float* Ws      = (const float*)d_in[25];
    const float* bs      = (const float*)d_in[26];
    const float* addw    = (const float*)d_in[27];
    float* out = (float*)d_out;
    float* ws  = (float*)d_ws;

    // workspace layout (float offsets)
    short* WvB  = (short*)ws;                     // 32768 f
    short* W1B  = (short*)(ws + 32768);           // 32768 f
    short* W3B  = (short*)(ws + 65536);           // 32768 f
    short* WB2  = (short*)(ws + 98304);           // 294912 f
    float* ycxc = ws + 405504;                    // 256
    float* S    = ws + 405760;                    // 36864
    float* sigw = ws + 442624;                    // 128
    float* gmap = ws + 442752;                    // 65536
    float* bmap = ws + 508288;                    // 65536
    float* zbuf = ws + 573824;                    // 16 (zeros, written by prep)
    __hip_bfloat16* bufA = (__hip_bfloat16*)(ws + 573840);   // 16.78M bf16 NHWC
    __hip_bfloat16* bufB = (__hip_bfloat16*)(ws + 8962448);  // 16.78M bf16 NHWC

    prep_kernel<<<2560, 256, 0, stream>>>(Wv, Wf1, Wf3, Wf2, WvB, W1B, W3B, WB2, zbuf);
    langmlp_kernel<<<16, 448, 0, stream>>>(flang, wmask, W1, b1, W2, b2, ycxc);
    wsum_kernel<<<4096, 256, 0, stream>>>(img, S);
    sigw_kernel<<<16, 256, 0, stream>>>(Ws, S, bs, sigw);
    gauss_kernel<<<1024, 64, 0, stream>>>(ycxc, sigw, sigma_w, Wg, sg, bg, Wb, sb, bb, gmap, bmap);
    // f1 = silu(Wf1 * l2norm(g*tanh(silu(Wv*img*sv+bv)) + bmax) * sf1 + bf1) -> bufB (bf16 NHWC)
    f01_kernel<<<1024, 256, 0, stream>>>(img, WvB, W1B, sv, bv, sf1, bf1, gmap, bmap, bufB);
    // f2 = silu(Wf2(3x3)*f1*sf2+bf2) -> bufA (bf16 NHWC)
    conv3x3_mfma<<<512, 256, 0, stream>>>(bufB, WB2, sf2, bf2, zbuf, bufA);
    // out = l2norm((1+aw)*img + (1-aw)*(Wf3*f2 + bf3)) -> d_out (fp32 NCHW)
    final_mfma<<<1024, 256, 0, stream>>>(bufA, W3B, bf3, img, addw, out);
}

// Round 7
// 416.010 us; speedup vs baseline: 1.1247x; 1.0084x over previous
//
#include <hip/hip_runtime.h>
#include <hip/hip_bf16.h>

// Problem: B=16, C=256, H=64, L=40, TD=768, NC=8, EMB=392
// R7: dispatch-count collapse 8 -> 3 (measured ~15-20us per-dispatch overhead).
//   mega1 = prep + wsum + langmlp (block-partitioned, independent work)
//   f01'  = sigw-recompute + gauss + Wv GEMM + FiLM + l2norm + Wf1 GEMM
//   c3f   = conv3x3 (async dbuf) + Wf3 GEMM (from LDS restage) + v_add + l2norm

#define DEVFN static __device__ __forceinline__

DEVFN float sigmoidf_(float x) { return 1.f / (1.f + expf(-x)); }       // precise
DEVFN float siluf_(float y) { return y / (1.f + __expf(-y)); }          // fast
DEVFN float tanh_fast_(float x) { return 1.f - 2.f / (__expf(2.f * x) + 1.f); }

typedef __attribute__((ext_vector_type(8))) short bf16x8;
typedef __attribute__((ext_vector_type(4))) float f32x4;

DEVFN unsigned short f2bf_(float f) {
    union { __hip_bfloat16 b; unsigned short u; } cv;
    cv.b = __float2bfloat16(f);
    return cv.u;
}
DEVFN float bf2f_(unsigned short u) {
    union { unsigned short u; __hip_bfloat16 b; } cv;
    cv.u = u;
    return __bfloat162float(cv.b);
}

DEVFN void async_cp16(const void* g, void* l) {
    __builtin_amdgcn_global_load_lds(
        (const __attribute__((address_space(1))) unsigned int*)g,
        (__attribute__((address_space(3))) unsigned int*)l, 16, 0, 0);
}

// ================= mega1: prep (0..2559) | wsum (2560..6655) | langmlp (6656..6671) =================
__global__ __launch_bounds__(256) void mega1_kernel(
        const float* __restrict__ Wv, const float* __restrict__ Wf1,
        const float* __restrict__ Wf3, const float* __restrict__ Wf2,
        short* __restrict__ WvB, short* __restrict__ W1B,
        short* __restrict__ W3B, short* __restrict__ WB2,
        float* __restrict__ zbuf,
        const float* __restrict__ img, float* __restrict__ S,
        const float* __restrict__ flang, const int* __restrict__ mask,
        const float* __restrict__ Wm1, const float* __restrict__ bm1,
        const float* __restrict__ Wm2, const float* __restrict__ bm2,
        float* __restrict__ ycxc) {
    __shared__ float red[9 * 256];          // wsum
    __shared__ float inc[40];               // langmlp
    __shared__ float isum;
    __shared__ float fa[768];
    __shared__ float h[392];
    __shared__ float o[16];
    int bid = blockIdx.x, t = threadIdx.x;

    if (bid < 2560) {
        // -------- prep: weight packing + zero scratch --------
        int idx = bid * 256 + t;
        if (idx < 8) zbuf[idx] = 0.f;
        if (idx < 65536) {
            int j    = idx & 7;
            int lane = (idx >> 3) & 63;
            int coT  = (idx >> 9) & 15;
            int ci32 = (idx >> 13) & 7;
            int co = coT * 16 + (lane & 15);
            int ci = ci32 * 32 + ((lane >> 4) << 3) + j;
            int src = co * 256 + ci;
            WvB[idx] = (short)f2bf_(Wv[src]);
            W1B[idx] = (short)f2bf_(Wf1[src]);
            W3B[idx] = (short)f2bf_(Wf3[src]);
        }
        int oo = idx - 65536;
        if (oo >= 0 && oo < 589824) {
            int j    = oo & 7;
            int lane = (oo >> 3) & 63;
            int coT  = (oo >> 9) & 15;
            int ci32 = (oo >> 13) & 7;
            int kk   = oo >> 16;
            int co = coT * 16 + (lane & 15);
            int ci = ci32 * 32 + ((lane >> 4) << 3) + j;
            WB2[oo] = (short)f2bf_(Wf2[(co * 256 + ci) * 9 + kk]);
        }
    } else if (bid < 6656) {
        // -------- wsum: 9 shifted window sums per (b,ci) --------
        int bc = bid - 2560;
        float s[9];
#pragma unroll
        for (int k = 0; k < 9; ++k) s[k] = 0.f;
        const float* p = img + (size_t)bc * 4096;
        for (int j = 0; j < 16; ++j) {
            int idx = t + j * 256;
            int y = idx >> 6, x = idx & 63;
            float v = p[idx];
#pragma unroll
            for (int ky = 0; ky < 3; ++ky) {
                if (y < ky || y > ky + 61) continue;
#pragma unroll
                for (int kx = 0; kx < 3; ++kx) {
                    if (x < kx || x > kx + 61) continue;
                    s[ky * 3 + kx] += v;
                }
            }
        }
#pragma unroll
        for (int k = 0; k < 9; ++k) red[k * 256 + t] = s[k];
        __syncthreads();
        for (int st = 128; st > 0; st >>= 1) {
            if (t < st) {
#pragma unroll
                for (int k = 0; k < 9; ++k) red[k * 256 + t] += red[k * 256 + t + st];
            }
            __syncthreads();
        }
        if (t < 9) S[(size_t)bc * 9 + t] = red[t * 256];
    } else {
        // -------- langmlp (256-thread variant) --------
        int b = bid - 6656;
        if (t == 0) {
            float cum[40];
            float c = 0.f;
            for (int l = 0; l < 40; ++l) { c += (float)mask[b * 40 + l]; cum[l] = c; }
            float tot = c, sm = 0.f;
            for (int l = 0; l < 40; ++l) {
                float m = (float)mask[b * 40 + l];
                float v = (cum[l] > 1.f && cum[l] < tot) ? m : 0.f;
                inc[l] = v; sm += v;
            }
            isum = sm;
        }
        __syncthreads();
        for (int d = t; d < 768; d += 256) {
            float a = 0.f;
            for (int l = 0; l < 40; ++l) a += flang[(size_t)(b * 40 + l) * 768 + d] * inc[l];
            fa[d] = a / isum;
        }
        __syncthreads();
        for (int u = t; u < 392; u += 256) {
            float a = bm1[u];
            const float* w = Wm1 + (size_t)u * 768;
            for (int k = 0; k < 768; ++k) a = fmaf(fa[k], w[k], a);
            h[u] = a;
        }
        __syncthreads();
        if (t < 16) {
            float a = bm2[t];
            const float* w = Wm2 + (size_t)t * 392;
            for (int k = 0; k < 392; ++k) a = fmaf(h[k], w[k], a);
            o[t] = sigmoidf_(a);
        }
        __syncthreads();
        if (t < 8) {
            ycxc[b * 8 + t]       = (float)(int)(o[2 * t] * 64.f);
            ycxc[128 + b * 8 + t] = (float)(int)(o[2 * t + 1] * 64.f);
        }
    }
}

// ================= f01': sigw + gauss + Wv GEMM + FiLM + l2norm + Wf1 GEMM =================
__global__ __launch_bounds__(256) void f01_kernel(
        const float* __restrict__ img, const short* __restrict__ wvb,
        const short* __restrict__ w1b,
        const float* __restrict__ sv, const float* __restrict__ bv,
        const float* __restrict__ s1, const float* __restrict__ b1,
        const float* __restrict__ S, const float* __restrict__ Ws,
        const float* __restrict__ bs, const float* __restrict__ ycxc,
        const float* __restrict__ sigma_w,
        const float* __restrict__ Wg, const float* __restrict__ sg,
        const float* __restrict__ bg,
        const float* __restrict__ Wb, const float* __restrict__ sb,
        const float* __restrict__ bb,
        __hip_bfloat16* __restrict__ outB) {
    __shared__ __attribute__((aligned(16))) short lA[64 * 264];   // 33792 B (aliased: red, pr)
    __shared__ float invs[64];
    __shared__ float ls_sv[256], ls_bv[256], ls_s1[256], ls_b1[256];
    __shared__ float ls_g[64], ls_bm[64];
    __shared__ float sigw8[8];
    float* red = (float*)lA;                                       // phase A alias
    float* pr  = (float*)lA;                                       // film alias (sequenced)
    int blk = blockIdx.x, b = blk >> 6, y = blk & 63;
    int t = threadIdx.x, w = t >> 6, lane = t & 63;
    int lx = lane & 15, koct = lane >> 4;

    ls_sv[t] = sv[t]; ls_bv[t] = bv[t];
    ls_s1[t] = s1[t]; ls_b1[t] = b1[t];

    // ---- phase A: sigw recompute for this b (red aliases lA) ----
    {
        float s9[9];
        const float* Sp = S + (size_t)(b * 256 + t) * 9;
#pragma unroll
        for (int k = 0; k < 9; ++k) s9[k] = Sp[k];
#pragma unroll
        for (int co = 0; co < 8; ++co) {
            const float* wp = Ws + (size_t)(co * 256 + t) * 9;
            float a = 0.f;
#pragma unroll
            for (int k = 0; k < 9; ++k) a = fmaf(wp[k], s9[k], a);
            red[co * 256 + t] = a;
        }
        __syncthreads();
        for (int st = 128; st > 0; st >>= 1) {
            if (t < st) {
#pragma unroll
                for (int co = 0; co < 8; ++co) red[co * 256 + t] += red[co * 256 + t + st];
            }
            __syncthreads();
        }
        if (t < 8) sigw8[t] = sigmoidf_(red[t * 256] / 3844.f + bs[t]);
        __syncthreads();
    }

    // ---- phase B: gaussian -> gamma/beta -> ls_g, ls_bm for this row ----
    if (t < 64) {
        float sx = sigma_w[0] * 64.f;
        float wv8[8];
#pragma unroll
        for (int n = 0; n < 8; ++n) {
            float yc = ycxc[b * 8 + n], xc = ycxc[128 + b * 8 + n];
            float sy = sx * sigw8[n];
            float dy = (float)y - yc, dx = (float)t - xc;
            wv8[n] = expf(-(dy * dy / (2.f * sy * sy) + dx * dx / (2.f * sx * sx)));
        }
        float gacc = 0.f, bmax = -3.4e38f;
#pragma unroll
        for (int n = 0; n < 8; ++n) {
            float a1 = 0.f, a2 = 0.f;
#pragma unroll
            for (int m = 0; m < 8; ++m) {
                a1 = fmaf(Wg[n * 8 + m], wv8[m], a1);
                a2 = fmaf(Wb[n * 8 + m], wv8[m], a2);
            }
            float ga = tanhf(siluf_(a1 * sg[n] + bg[n]));
            float be = tanhf(siluf_(a2 * sb[n] + bb[n]));
            gacc += ga;
            bmax = fmaxf(bmax, be);
        }
        ls_g[t]  = gacc * 0.125f;
        ls_bm[t] = bmax;
    }

    // ---- stage img (fp32 NCHW) -> lA bf16 [x][ci] ----
    {
        int x = t & 63, cg = t >> 6;
        const float* ib = img + (size_t)b * 1048576 + y * 64 + x;
#pragma unroll
        for (int c8 = 0; c8 < 8; ++c8) {
            int ci0 = cg * 64 + c8 * 8;
            unsigned short r[8];
#pragma unroll
            for (int j = 0; j < 8; ++j) r[j] = f2bf_(ib[(size_t)(ci0 + j) * 4096]);
            *(uint4*)&lA[x * 264 + ci0] = *(uint4*)r;
        }
    }
    f32x4 acc[4][4];
#pragma unroll
    for (int mi = 0; mi < 4; ++mi)
#pragma unroll
        for (int ni = 0; ni < 4; ++ni) acc[mi][ni] = (f32x4){0.f, 0.f, 0.f, 0.f};
    __syncthreads();

    // ---- GEMM1: Wv ----
#pragma unroll
    for (int k32 = 0; k32 < 8; ++k32) {
        const short* wp = wvb + (((k32 * 16) + w * 4) * 64 + lane) * 8;
        bf16x8 bfr[4];
#pragma unroll
        for (int ni = 0; ni < 4; ++ni) bfr[ni] = *(const bf16x8*)(wp + ni * 512);
        bf16x8 afr[4];
#pragma unroll
        for (int mi = 0; mi < 4; ++mi)
            afr[mi] = *(const bf16x8*)&lA[(mi * 16 + lx) * 264 + k32 * 32 + koct * 8];
#pragma unroll
        for (int mi = 0; mi < 4; ++mi)
#pragma unroll
            for (int ni = 0; ni < 4; ++ni)
                acc[mi][ni] = __builtin_amdgcn_mfma_f32_16x16x32_bf16(afr[mi], bfr[ni], acc[mi][ni], 0, 0, 0);
    }
    __syncthreads();   // lA (img) dead; pr may now be written

    // ---- FiLM epilogue + partial l2 ----
#pragma unroll
    for (int mi = 0; mi < 4; ++mi)
#pragma unroll
        for (int rr = 0; rr < 4; ++rr) {
            int x = mi * 16 + koct * 4 + rr;
            float ps = 0.f;
#pragma unroll
            for (int ni = 0; ni < 4; ++ni) {
                int co = w * 64 + ni * 16 + lx;
                float yv = fmaf(acc[mi][ni][rr], ls_sv[co], ls_bv[co]);
                float mvv = tanh_fast_(siluf_(yv));
                float v = fmaf(ls_g[x], mvv, ls_bm[x]);
                acc[mi][ni][rr] = v;
                ps += v * v;
            }
            pr[x * 64 + w * 16 + lx] = ps;
        }
    __syncthreads();
    if (t < 64) {
        float s2 = 0.f;
        for (int q = 0; q < 64; ++q) s2 += pr[t * 64 + q];
        invs[t] = 1.f / fmaxf(sqrtf(s2), 1e-12f);
    }
    __syncthreads();   // pr dead; lA may be rewritten (v)

    // ---- v (normalized) -> lA bf16 [x][ci] ----
#pragma unroll
    for (int mi = 0; mi < 4; ++mi)
#pragma unroll
        for (int ni = 0; ni < 4; ++ni) {
            int co = w * 64 + ni * 16 + lx;
#pragma unroll
            for (int rr = 0; rr < 4; ++rr) {
                int x = mi * 16 + koct * 4 + rr;
                lA[x * 264 + co] = (short)f2bf_(acc[mi][ni][rr] * invs[x]);
            }
        }
#pragma unroll
    for (int mi = 0; mi < 4; ++mi)
#pragma unroll
        for (int ni = 0; ni < 4; ++ni) acc[mi][ni] = (f32x4){0.f, 0.f, 0.f, 0.f};
    __syncthreads();

    // ---- GEMM2: Wf1 ----
#pragma unroll
    for (int k32 = 0; k32 < 8; ++k32) {
        const short* wp = w1b + (((k32 * 16) + w * 4) * 64 + lane) * 8;
        bf16x8 bfr[4];
#pragma unroll
        for (int ni = 0; ni < 4; ++ni) bfr[ni] = *(const bf16x8*)(wp + ni * 512);
        bf16x8 afr[4];
#pragma unroll
        for (int mi = 0; mi < 4; ++mi)
            afr[mi] = *(const bf16x8*)&lA[(mi * 16 + lx) * 264 + k32 * 32 + koct * 8];
#pragma unroll
        for (int mi = 0; mi < 4; ++mi)
#pragma unroll
            for (int ni = 0; ni < 4; ++ni)
                acc[mi][ni] = __builtin_amdgcn_mfma_f32_16x16x32_bf16(afr[mi], bfr[ni], acc[mi][ni], 0, 0, 0);
    }
    __syncthreads();

    // ---- silu -> lA [x][co] -> NHWC store ----
#pragma unroll
    for (int mi = 0; mi < 4; ++mi)
#pragma unroll
        for (int ni = 0; ni < 4; ++ni) {
            int co = w * 64 + ni * 16 + lx;
#pragma unroll
            for (int rr = 0; rr < 4; ++rr) {
                int x = mi * 16 + koct * 4 + rr;
                float yv = fmaf(acc[mi][ni][rr], ls_s1[co], ls_b1[co]);
                lA[x * 264 + co] = (short)f2bf_(siluf_(yv));
            }
        }
    __syncthreads();
    unsigned short* og = (unsigned short*)outB + (size_t)(b * 64 + y) * 16384;
#pragma unroll
    for (int it = 0; it < 8; ++it) {
        int e8 = t + it * 256;
        int x2 = e8 >> 5, c8 = e8 & 31;
        *(uint4*)(og + e8 * 8) = *(uint4*)&lA[x2 * 264 + c8 * 8];
    }
}

// ================= c3f: conv3x3 (async dbuf) + Wf3 GEMM + v_add + l2norm =================
DEVFN void stage_chunk(const unsigned short* __restrict__ xg, short* ldsbuf,
                       const unsigned short* __restrict__ zbuf, int cc, int y0, int t) {
#pragma unroll
    for (int p = 0; p < 10; ++p) {
        int slot = t + p * 256;
        if (slot < 2376) {                       // 4 rows * 66 xp * 9
            int r = slot / 594;
            int rem = slot - r * 594;
            int xp = rem / 9;
            int oct = rem - xp * 9;
            int ys = y0 + r - 1, xs = xp - 1;
            bool valid = (oct < 8) && (ys >= 0) && (ys < 64) && (xs >= 0) && (xs < 64);
            const unsigned short* gp = valid ? (xg + ((ys * 64 + xs) * 256 + cc * 64 + oct * 8))
                                             : zbuf;
            async_cp16(gp, ldsbuf + slot * 8);
        }
    }
}

__global__ __launch_bounds__(256, 2) void c3f_kernel(const __hip_bfloat16* __restrict__ xin,
                                                     const short* __restrict__ wb,
                                                     const float* __restrict__ sc,
                                                     const float* __restrict__ bi,
                                                     const float* __restrict__ zbufF,
                                                     const short* __restrict__ w3b,
                                                     const float* __restrict__ bf3,
                                                     const float* __restrict__ img,
                                                     const float* __restrict__ addw,
                                                     float* __restrict__ outF) {
    __shared__ __attribute__((aligned(16))) short lds[2][19008];   // 2 x 38016 B
    __shared__ float pr2[256];
    __shared__ float invs[64];
    __shared__ float ls_b3[256];
    int blk = blockIdx.x;
    int b = blk >> 5, y0 = (blk & 31) * 2;
    int t = threadIdx.x;
    int w = t >> 6, lane = t & 63;
    int lx = lane & 15, koct = lane >> 4;
    const unsigned short* xg = (const unsigned short*)xin + (size_t)b * 1048576;
    const unsigned short* zbuf = (const unsigned short*)zbufF;
    ls_b3[t] = bf3[t];

    f32x4 acc[8][4];
#pragma unroll
    for (int mi = 0; mi < 8; ++mi)
#pragma unroll
        for (int ni = 0; ni < 4; ++ni) acc[mi][ni] = (f32x4){0.f, 0.f, 0.f, 0.f};

    stage_chunk(xg, lds[0], zbuf, 0, y0, t);
    __syncthreads();

    for (int cc = 0; cc < 4; ++cc) {        // ci chunks of 64
        short* cur = lds[cc & 1];
        if (cc < 3) stage_chunk(xg, lds[(cc + 1) & 1], zbuf, cc + 1, y0, t);
        for (int kk = 0; kk < 9; ++kk) {
            int ky = kk / 3, kx = kk - ky * 3;
#pragma unroll
            for (int k32 = 0; k32 < 2; ++k32) {
                const short* wp = wb + ((((kk * 8 + cc * 2 + k32) * 16) + w * 4) * 64 + lane) * 8;
                bf16x8 bfr[4];
#pragma unroll
                for (int ni = 0; ni < 4; ++ni)
                    bfr[ni] = *(const bf16x8*)(wp + ni * 512);
                bf16x8 afr[8];
#pragma unroll
                for (int mi = 0; mi < 8; ++mi) {
                    int row = mi >> 2, xb = (mi & 3) * 16;
                    afr[mi] = *(const bf16x8*)&cur[((row + ky) * 66 + xb + lx + kx) * 72 + k32 * 32 + koct * 8];
                }
#pragma unroll
                for (int mi = 0; mi < 8; ++mi)
#pragma unroll
                    for (int ni = 0; ni < 4; ++ni)
                        acc[mi][ni] = __builtin_amdgcn_mfma_f32_16x16x32_bf16(afr[mi], bfr[ni], acc[mi][ni], 0, 0, 0);
            }
        }
        __syncthreads();
    }

    // ---- fused final: per row, Wf3 GEMM from LDS restage + v_add + l2norm ----
    float aw = tanhf(addw[0]);
    float ca = 1.f + aw, cb = 1.f - aw;
    short* ep  = &lds[0][0];    // f2 bf16 [x][ci], stride 264
    short* wst = &lds[1][0];    // w  bf16 [co][x], stride 66
#pragma unroll
    for (int r2 = 0; r2 < 2; ++r2) {
        // f2 row: silu(acc*sc+bi) -> ep [x][ci]
#pragma unroll
        for (int mi4 = 0; mi4 < 4; ++mi4) {
            int mi = r2 * 4 + mi4;
#pragma unroll
            for (int ni = 0; ni < 4; ++ni) {
                int co = w * 64 + ni * 16 + lx;
                float s = sc[co], bb2 = bi[co];
#pragma unroll
                for (int rr = 0; rr < 4; ++rr) {
                    int x = mi4 * 16 + koct * 4 + rr;
                    float yv = fmaf(acc[mi][ni][rr], s, bb2);
                    ep[x * 264 + co] = (short)f2bf_(siluf_(yv));
                }
            }
        }
        __syncthreads();
        // GEMM2: Wf3 on this row
        f32x4 acc2[4][4];
#pragma unroll
        for (int mi = 0; mi < 4; ++mi)
#pragma unroll
            for (int ni = 0; ni < 4; ++ni) acc2[mi][ni] = (f32x4){0.f, 0.f, 0.f, 0.f};
#pragma unroll
        for (int k32 = 0; k32 < 8; ++k32) {
            const short* wp = w3b + (((k32 * 16) + w * 4) * 64 + lane) * 8;
            bf16x8 bfr[4];
#pragma unroll
            for (int ni = 0; ni < 4; ++ni) bfr[ni] = *(const bf16x8*)(wp + ni * 512);
            bf16x8 afr[4];
#pragma unroll
            for (int mi = 0; mi < 4; ++mi)
                afr[mi] = *(const bf16x8*)&ep[(mi * 16 + lx) * 264 + k32 * 32 + koct * 8];
#pragma unroll
            for (int mi = 0; mi < 4; ++mi)
#pragma unroll
                for (int ni = 0; ni < 4; ++ni)
                    acc2[mi][ni] = __builtin_amdgcn_mfma_f32_16x16x32_bf16(afr[mi], bfr[ni], acc2[mi][ni], 0, 0, 0);
        }
        // w = acc2 + bf3 -> wst bf16 [co][x] (v_film << img; bf16 ok)
#pragma unroll
        for (int mi = 0; mi < 4; ++mi)
#pragma unroll
            for (int ni = 0; ni < 4; ++ni) {
                int co = w * 64 + ni * 16 + lx;
                float b3 = ls_b3[co];
#pragma unroll
                for (int rr = 0; rr < 4; ++rr) {
                    int x = mi * 16 + koct * 4 + rr;
                    wst[co * 66 + x] = (short)f2bf_(acc2[mi][ni][rr] + b3);
                }
            }
        __syncthreads();
        // coalesced two-pass: v = ca*img + cb*w ; l2norm over co ; store fp32 NCHW
        int x = t & 63, cg = t >> 6;
        const float* ip = img + (size_t)b * 1048576 + (size_t)(y0 + r2) * 64 + x;
        float ss = 0.f;
#pragma unroll 8
        for (int j = 0; j < 64; ++j) {
            int co = cg * 64 + j;
            float v = fmaf(cb, bf2f_((unsigned short)wst[co * 66 + x]), ca * ip[(size_t)co * 4096]);
            ss += v * v;
        }
        pr2[cg * 64 + x] = ss;
        __syncthreads();
        if (t < 64)
            invs[t] = 1.f / fmaxf(sqrtf(pr2[t] + pr2[64 + t] + pr2[128 + t] + pr2[192 + t]), 1e-12f);
        __syncthreads();
        float iv = invs[x];
        float* op = outF + (size_t)b * 1048576 + (size_t)(y0 + r2) * 64 + x;
#pragma unroll 8
        for (int j = 0; j < 64; ++j) {
            int co = cg * 64 + j;
            float v = fmaf(cb, bf2f_((unsigned short)wst[co * 66 + x]), ca * ip[(size_t)co * 4096]);
            op[(size_t)co * 4096] = v * iv;
        }
        __syncthreads();
    }
}

// ---------------- launch ----------------
extern "C" void kernel_launch(void* const* d_in, const int* in_sizes, int n_in,
                              void* d_out, int out_size, void* d_ws, size_t ws_size,
                              hipStream_t stream) {
    const float* img     = (const float*)d_in[0];
    const float* flang   = (const float*)d_in[1];
    const int*   wmask   = (const int*)d_in[2];
    const float* sigma_w = (const float*)d_in[3];
    const float* W1      = (const float*)d_in[4];
    const float* b1      = (const float*)d_in[5];
    const float* W2      = (const float*)d_in[6];
    const float* b2      = (const float*)d_in[7];
    const float* Wv      = (const float*)d_in[8];
    const float* sv      = (const float*)d_in[9];
    const float* bv      = (const float*)d_in[10];
    const float* Wg      = (const float*)d_in[11];
    const float* sg      = (const float*)d_in[12];
    const float* bg      = (const float*)d_in[13];
    const float* Wb      = (const float*)d_in[14];
    const float* sb      = (const float*)d_in[15];
    const float* bb      = (const float*)d_in[16];
    const float* Wf1     = (const float*)d_in[17];
    const float* sf1     = (const float*)d_in[18];
    const float* bf1     = (const float*)d_in[19];
    const float* Wf2     = (const float*)d_in[20];
    const float* sf2     = (const float*)d_in[21];
    const float* bf2     = (const float*)d_in[22];
    const float* Wf3     = (const float*)d_in[23];
    const float* bf3     = (const float*)d_in[24];
    const float* Ws      = (const float*)d_in[25];
    const float* bs      = (const float*)d_in[26];
    const float* addw    = (const float*)d_in[27];
    float* out = (float*)d_out;
    float* ws  = (float*)d_ws;

    // workspace layout (float offsets)
    short* WvB  = (short*)ws;                     // 32768 f
    short* W1B  = (short*)(ws + 32768);           // 32768 f
    short* W3B  = (short*)(ws + 65536);           // 32768 f
    short* WB2  = (short*)(ws + 98304);           // 294912 f -> ends 393216
    float* ycxc = ws + 393216;                    // 256
    float* S    = ws + 393472;                    // 36864 -> ends 430336
    float* zbuf = ws + 430336;                    // 16 (zeros, written by mega1 block 0)
    __hip_bfloat16* bufB = (__hip_bfloat16*)(ws + 430352);   // 16.78M bf16 NHWC

    // 1) prep + wsum + langmlp (independent)
    mega1_kernel<<<6672, 256, 0, stream>>>(Wv, Wf1, Wf3, Wf2, WvB, W1B, W3B, WB2, zbuf,
                                           img, S, flang, wmask, W1, b1, W2, b2, ycxc);
    // 2) f1 = silu(Wf1 * l2norm(g*tanh(silu(Wv*img*sv+bv)) + bmax) * sf1 + bf1)  (sigw+gauss inline)
    f01_kernel<<<1024, 256, 0, stream>>>(img, WvB, W1B, sv, bv, sf1, bf1,
                                         S, Ws, bs, ycxc, sigma_w,
                                         Wg, sg, bg, Wb, sb, bb, bufB);
    // 3) f2 = silu(Wf2(3x3)*f1) ; out = l2norm((1+aw)*img + (1-aw)*(Wf3*f2 + bf3))
    c3f_kernel<<<512, 256, 0, stream>>>(bufB, WB2, sf2, bf2, zbuf, W3B, bf3, img, addw, out);
}